// Round 2
// baseline (528.525 us; speedup 1.0000x reference)
//
#include <hip/hip_runtime.h>

// Frozen problem constants
#define RAD   4
#define DIM   256

// Normalized 1-D Gaussian weights for R=4, sigma=1.2 (fp32; matches the
// reference's expf/sum arithmetic to ~1e-7, vs threshold 1.08e-1).
__device__ __constant__ float GW[9] = {
    0.00128537f, 0.01460861f, 0.08290688f, 0.23495379f, 0.33249030f,
    0.23495379f, 0.08290688f, 0.01460861f, 0.00128537f
};

// ---------------------------------------------------------------------------
// Fused kernel: float4 grid-stride copy; threads whose 4 voxels overlap any
// point-box compute the 9^3 zero-padded Gaussian conv for the inside voxels.
// ---------------------------------------------------------------------------
template <int NPT>
__global__ __launch_bounds__(256) void fused_blur_copy(
    const float* __restrict__ vol, const int* __restrict__ pts,
    float* __restrict__ out, int n4) {
    // Point coords -> registers (compile-time NPT, fully unrolled => no scratch)
    int pz[NPT], py[NPT], px[NPT];
    #pragma unroll
    for (int p = 0; p < NPT; ++p) {
        pz[p] = pts[3 * p + 0];
        py[p] = pts[3 * p + 1];
        px[p] = pts[3 * p + 2];
    }

    const float4* __restrict__ in4  = (const float4*)vol;
    float4* __restrict__       out4 = (float4*)out;

    const int stride = gridDim.x * blockDim.x;
    for (int i4 = blockIdx.x * blockDim.x + threadIdx.x; i4 < n4; i4 += stride) {
        float4 v = in4[i4];
        const int lin = i4 << 2;
        const int x0 = lin & (DIM - 1);
        const int y  = (lin >> 8) & (DIM - 1);
        const int z  = lin >> 16;

        // Does this float4 overlap any box?
        bool hit = false;
        #pragma unroll
        for (int p = 0; p < NPT; ++p) {
            bool h = (abs(z - pz[p]) <= RAD) & (abs(y - py[p]) <= RAD) &
                     (x0 <= px[p] + RAD) & (x0 + 3 >= px[p] - RAD);
            hit = hit | h;
        }

        if (__builtin_expect((int)hit, 0)) {
            float r[4] = {v.x, v.y, v.z, v.w};
            #pragma unroll
            for (int e = 0; e < 4; ++e) {
                const int x = x0 + e;
                bool inside = false;
                #pragma unroll
                for (int p = 0; p < NPT; ++p) {
                    bool h = (abs(z - pz[p]) <= RAD) & (abs(y - py[p]) <= RAD) &
                             (abs(x - px[p]) <= RAD);
                    inside = inside | h;
                }
                if (inside) {
                    // Direct 9^3 conv, zero padding == clamp loop bounds.
                    const int zlo = max(z - RAD, 0), zhi = min(z + RAD, DIM - 1);
                    const int ylo = max(y - RAD, 0), yhi = min(y + RAD, DIM - 1);
                    const int xlo = max(x - RAD, 0), xhi = min(x + RAD, DIM - 1);
                    float acc = 0.f;
                    for (int zz = zlo; zz <= zhi; ++zz) {
                        const float wz = GW[zz - z + RAD];
                        for (int yy = ylo; yy <= yhi; ++yy) {
                            const float wzy = wz * GW[yy - y + RAD];
                            const float* __restrict__ row =
                                vol + (zz << 16) + (yy << 8);
                            for (int xx = xlo; xx <= xhi; ++xx)
                                acc += wzy * GW[xx - x + RAD] * row[xx];
                        }
                    }
                    r[e] = acc;
                }
            }
            float4 o; o.x = r[0]; o.y = r[1]; o.z = r[2]; o.w = r[3];
            out4[i4] = o;
        } else {
            out4[i4] = v;
        }
    }
}

extern "C" void kernel_launch(void* const* d_in, const int* in_sizes, int n_in,
                              void* d_out, int out_size, void* d_ws, size_t ws_size,
                              hipStream_t stream) {
    const float* vol = (const float*)d_in[0];
    const int*   pts = (const int*)d_in[1];
    float*       out = (float*)d_out;

    const int n   = in_sizes[0];       // 256^3
    const int n4  = n / 4;
    const int npt = in_sizes[1] / 3;   // 6 (reference range 5..7)

    const int blocks = 2048;
    switch (npt) {
        case 1: fused_blur_copy<1><<<blocks, 256, 0, stream>>>(vol, pts, out, n4); break;
        case 2: fused_blur_copy<2><<<blocks, 256, 0, stream>>>(vol, pts, out, n4); break;
        case 3: fused_blur_copy<3><<<blocks, 256, 0, stream>>>(vol, pts, out, n4); break;
        case 4: fused_blur_copy<4><<<blocks, 256, 0, stream>>>(vol, pts, out, n4); break;
        case 5: fused_blur_copy<5><<<blocks, 256, 0, stream>>>(vol, pts, out, n4); break;
        case 6: fused_blur_copy<6><<<blocks, 256, 0, stream>>>(vol, pts, out, n4); break;
        default: fused_blur_copy<7><<<blocks, 256, 0, stream>>>(vol, pts, out, n4); break;
    }
}

// Round 3
// 124.987 us; speedup vs baseline: 4.2287x; 4.2287x over previous
//
#include <hip/hip_runtime.h>

// Frozen problem constants
#define RAD   4
#define KS    9          // kernel size 2R+1
#define HALO  8          // 2*RAD
#define SS    17         // KS + 2*RAD (staged neighborhood per dim)
#define DIM   256        // volume is 256^3
#define SIG   1.2f

// ---------------------------------------------------------------------------
// Kernel 1: vectorized copy volume -> out (float4, grid-stride).
// Plain body (no internal branches) so the compiler unrolls and keeps
// multiple loads in flight — the round-2 fused variant with a divergent
// branch in this loop collapsed to ~1 load in flight and ran 20x slower.
// ---------------------------------------------------------------------------
__global__ __launch_bounds__(256) void copy_vol_kernel(
    const float4* __restrict__ in, float4* __restrict__ out, int n4) {
    int stride = gridDim.x * blockDim.x;
    for (int i = blockIdx.x * blockDim.x + threadIdx.x; i < n4; i += stride) {
        out[i] = in[i];
    }
}

// ---------------------------------------------------------------------------
// Kernel 2: per-point blur fix-up. One block per point.
//   Stage 17^3 neighborhood (zero-filled OOB, = zero-padded conv), then
//   separable z/y/x Gaussian passes in LDS, write clipped 9^3 outputs.
//   Overlapping boxes write bitwise-identical values -> benign race.
//   Runs after the copy via stream ordering (required: copy would otherwise
//   overwrite blurred voxels).
// ---------------------------------------------------------------------------
__global__ __launch_bounds__(256) void blur_fix_kernel(
    const float* __restrict__ vol, const int* __restrict__ pts,
    float* __restrict__ out) {
    __shared__ float sm[SS * SS * SS];   // 4913 floats
    __shared__ float t1[KS * SS * SS];   // z-blurred: 9 x 17 x 17
    __shared__ float t2[KS * KS * SS];   // z+y-blurred: 9 x 9 x 17

    const int p  = blockIdx.x;
    const int tid = threadIdx.x;
    const int pz = pts[3 * p + 0];
    const int py = pts[3 * p + 1];
    const int px = pts[3 * p + 2];

    // Gaussian weights (normalized), same arithmetic as reference (fp32 exp)
    float g[KS];
    {
        float s = 0.f;
        #pragma unroll
        for (int i = 0; i < KS; ++i) {
            float x = (float)(i - RAD);
            g[i] = expf(-(x * x) / (2.f * SIG * SIG));
            s += g[i];
        }
        float inv = 1.f / s;
        #pragma unroll
        for (int i = 0; i < KS; ++i) g[i] *= inv;
    }

    // Stage 17^3 neighborhood centered at point, zeros outside the volume
    for (int idx = tid; idx < SS * SS * SS; idx += 256) {
        int k = idx % SS;
        int j = (idx / SS) % SS;
        int i = idx / (SS * SS);
        int z = pz - HALO + i;
        int y = py - HALO + j;
        int x = px - HALO + k;
        float v = 0.f;
        if ((unsigned)z < (unsigned)DIM && (unsigned)y < (unsigned)DIM &&
            (unsigned)x < (unsigned)DIM) {
            v = vol[((z * DIM) + y) * DIM + x];
        }
        sm[idx] = v;
    }
    __syncthreads();

    // Pass 1: blur along z.  Output i in [0,9) maps to z = pz - RAD + i.
    for (int idx = tid; idx < KS * SS * SS; idx += 256) {
        int k = idx % SS;
        int j = (idx / SS) % SS;
        int i = idx / (SS * SS);
        float acc = 0.f;
        #pragma unroll
        for (int t = 0; t < KS; ++t)
            acc += g[t] * sm[(((i + t) * SS) + j) * SS + k];
        t1[idx] = acc;
    }
    __syncthreads();

    // Pass 2: blur along y.
    for (int idx = tid; idx < KS * KS * SS; idx += 256) {
        int k = idx % SS;
        int j = (idx / SS) % KS;
        int i = idx / (SS * KS);
        float acc = 0.f;
        #pragma unroll
        for (int t = 0; t < KS; ++t)
            acc += g[t] * t1[((i * SS) + (j + t)) * SS + k];
        t2[((i * KS) + j) * SS + k] = acc;
    }
    __syncthreads();

    // Pass 3: blur along x + scatter the clipped 9^3 outputs.
    for (int idx = tid; idx < KS * KS * KS; idx += 256) {
        int k = idx % KS;
        int j = (idx / KS) % KS;
        int i = idx / (KS * KS);
        float acc = 0.f;
        #pragma unroll
        for (int t = 0; t < KS; ++t)
            acc += g[t] * t2[((i * KS) + j) * SS + (k + t)];
        int z = pz - RAD + i;
        int y = py - RAD + j;
        int x = px - RAD + k;
        if ((unsigned)z < (unsigned)DIM && (unsigned)y < (unsigned)DIM &&
            (unsigned)x < (unsigned)DIM) {
            out[((z * DIM) + y) * DIM + x] = acc;
        }
    }
}

extern "C" void kernel_launch(void* const* d_in, const int* in_sizes, int n_in,
                              void* d_out, int out_size, void* d_ws, size_t ws_size,
                              hipStream_t stream) {
    const float* vol = (const float*)d_in[0];
    const int*   pts = (const int*)d_in[1];
    float*       out = (float*)d_out;

    const int n   = in_sizes[0];          // 256^3 = 16777216
    const int n4  = n / 4;                // float4 count
    const int npt = in_sizes[1] / 3;      // 6 points

    copy_vol_kernel<<<2048, 256, 0, stream>>>(
        (const float4*)vol, (float4*)out, n4);
    blur_fix_kernel<<<npt, 256, 0, stream>>>(vol, pts, out);
}